// Round 17
// baseline (351.075 us; speedup 1.0000x reference)
//
#include <hip/hip_runtime.h>

// Gaussian pyramid, 4 levels. Input (16,3,1024,1024) f32.
// R17: UNFUSED. Every fused variant amplified the out0 copy-write stream
// (WRITE 402..741 MB vs 251 ideal; R2's unfused reduce was exactly clean).
// Structure: [reduce1 (cold im reads, out1 writes only)] -> [pure copy
// (im now L3-resident)] -> [reduce2] -> [reduce3]. All proven-clean patterns.

struct R12f { float4 A, B, C; };            // 12 consecutive input floats
struct W7 { float w0, w1, w2, w3, w4, w5, w6; float4 cp; };

template <int WIN>
__device__ __forceinline__ R12f load3(const float* ip, int iy, int xb) {
    const float4* p = (const float4*)(ip + (size_t)iy * WIN + xb);
    R12f r; r.A = p[0]; r.B = p[1]; r.C = p[2];
    return r;
}

__device__ __forceinline__ W7 extract(const R12f& r, bool L, bool Rr) {
    W7 o;
    o.w0 = L ? r.A.x : (Rr ? r.B.z : r.A.z);
    o.w1 = L ? r.A.x : (Rr ? r.B.w : r.A.w);
    o.w2 = L ? r.A.x : (Rr ? r.C.x : r.B.x);
    o.w3 = L ? r.A.y : (Rr ? r.C.y : r.B.y);
    o.w4 = L ? r.A.z : (Rr ? r.C.z : r.B.z);
    o.w5 = L ? r.A.w : (Rr ? r.C.w : r.B.w);
    o.w6 = L ? r.B.x : (Rr ? r.C.w : r.C.x);
    o.cp.x = o.w2; o.cp.y = o.w3; o.cp.z = o.w4; o.cp.w = o.w5;
    return o;
}

__device__ __forceinline__ float2 hconv2(const W7& w) {
    const float k0 = 0.0625f, k1 = 0.25f, k2 = 0.375f;
    float2 h;
    h.x = k0 * (w.w0 + w.w4) + k1 * (w.w1 + w.w3) + k2 * w.w2;   // out x=2g
    h.y = k0 * (w.w2 + w.w6) + k1 * (w.w3 + w.w5) + k2 * w.w4;   // out x=2g+1
    return h;
}

template <int R, int HIN, int WIN>
__global__ __launch_bounds__(256) void gpyr_slide(
        const float* __restrict__ in,
        float* __restrict__ out1) {
    constexpr int HOUT = HIN / 2, WOUT = WIN / 2;
    constexpr int GMAX = WIN / 4 - 1;
    const int tx = threadIdx.x, ty = threadIdx.y;
    const int g   = blockIdx.x * 64 + tx;      // lane's x-group (4 input floats)
    const int Y0  = (blockIdx.y * blockDim.y + ty) * R;
    const int img = blockIdx.z;

    const bool L  = (g == 0);
    const bool Rr = (g == GMAX);
    int xb = 4 * g - 4;
    if (L)  xb = 0;
    if (Rr) xb = 4 * g - 8;

    const float* ip = in + (size_t)img * HIN * WIN;
    float* o1 = out1 + (size_t)img * HOUT * WOUT;

    // Prologue: rows 2Y0-2, 2Y0-1, 2Y0.
    float2 hs0, hs1, hs2;
    {
        R12f t0 = load3<WIN>(ip, max(2 * Y0 - 2, 0), xb);
        R12f t1 = load3<WIN>(ip, max(2 * Y0 - 1, 0), xb);
        R12f t2 = load3<WIN>(ip, 2 * Y0, xb);
        W7 e0 = extract(t0, L, Rr); hs0 = hconv2(e0);
        W7 e1 = extract(t1, L, Rr); hs1 = hconv2(e1);
        W7 e2 = extract(t2, L, Rr); hs2 = hconv2(e2);
    }

    const float k0 = 0.0625f, k1 = 0.25f, k2 = 0.375f;

#pragma unroll
    for (int i = 0; i < R; ++i) {
        const int oy = Y0 + i;

        R12f ra = load3<WIN>(ip, 2 * oy + 1, xb);
        R12f rb = load3<WIN>(ip, min(2 * oy + 2, HIN - 1), xb);

        W7 ea = extract(ra, L, Rr);
        float2 ha = hconv2(ea);
        W7 eb = extract(rb, L, Rr);
        float2 hb = hconv2(eb);

        float2 o;
        o.x = k0 * (hs0.x + hb.x) + k1 * (hs1.x + ha.x) + k2 * hs2.x;
        o.y = k0 * (hs0.y + hb.y) + k1 * (hs1.y + ha.y) + k2 * hs2.y;
        *(float2*)(o1 + (size_t)oy * WOUT + 2 * g) = o;

        hs0 = hs2; hs1 = ha; hs2 = hb;          // slide down 2 input rows
    }
}

__global__ __launch_bounds__(256) void gpyr_copy(const float4* __restrict__ in,
                                                 float4* __restrict__ out, int n4) {
    int i = blockIdx.x * blockDim.x + threadIdx.x;
    int stride = gridDim.x * blockDim.x;
    for (; i < n4; i += stride) out[i] = in[i];
}

extern "C" void kernel_launch(void* const* d_in, const int* in_sizes, int n_in,
                              void* d_out, int out_size, void* d_ws, size_t ws_size,
                              hipStream_t stream) {
    const float* im = (const float*)d_in[0];
    float* out = (float*)d_out;

    const int NC = 16 * 3;
    const size_t L0 = (size_t)NC * 1024 * 1024;
    const size_t L1 = (size_t)NC * 512 * 512;
    const size_t L2 = (size_t)NC * 256 * 256;

    float* out0 = out;
    float* out1 = out0 + L0;
    float* out2 = out1 + L1;
    float* out3 = out2 + L2;

    // 1) Level-1 reduce first (cold im reads; out1 writes only — clean per R2).
    {
        dim3 block(64, 4, 1);
        dim3 grid(4, 512 / (4 * 8), NC);       // (4, 16, 48) = 3072
        gpyr_slide<8, 1024, 1024><<<grid, block, 0, stream>>>(im, out1);
    }
    // 2) Pure copy (im is now largely L3-resident -> read side cheap).
    {
        int n4 = (int)(L0 / 4);
        gpyr_copy<<<2048, 256, 0, stream>>>((const float4*)im, (float4*)out0, n4);
    }
    // 3) Level 2: R=2 for 2x blocks (3072) to dodge latency-bound tail.
    {
        dim3 block(64, 4, 1);
        dim3 grid(2, 256 / (4 * 2), NC);       // (2, 32, 48) = 3072
        gpyr_slide<2, 512, 512><<<grid, block, 0, stream>>>(out1, out2);
    }
    // 4) Level 3: R=1.
    {
        dim3 block(64, 4, 1);
        dim3 grid(1, 128 / 4, NC);             // (1, 32, 48) = 1536
        gpyr_slide<1, 256, 256><<<grid, block, 0, stream>>>(out2, out3);
    }
}